// Round 1
// baseline (233.141 us; speedup 1.0000x reference)
//
#include <hip/hip_runtime.h>

// SSIM (window=8 box SUMS, no normalization — matches the reference exactly).
// Inputs: groundtruth, noisy_img: (32, 3, 512, 512) fp32 -> 96 images of 512x512.
// Output: scalar fp32 = mean(1 - ssim_map) over 96 x 505 x 505.
//
// Strategy: block = (image, 32-output-row strip). 128 threads x float4 covers the
// full 512-wide row (no horizontal halo, perfect b128 coalescing). Vertical box
// sums slide in registers (8-row register ring for the subtract). Horizontal box
// sums via LDS: each thread publishes its 5 vertical-sum float4s, reads the two
// neighboring float4s per quantity (aligned ds_read_b128), then a 13-add sliding
// chain yields 4 outputs. One __syncthreads per output row (double-buffered LDS).

#define W 512
#define H 512
#define OW 505
#define OH 505
#define TH 32
#define NSTRIP ((OH + TH - 1) / TH)   // 16
#define NIMG 96
#define NPIX (96.0 * 505.0 * 505.0)   // 24482400

__device__ __forceinline__ float4 ld4(const float* p) { return *(const float4*)p; }
__device__ __forceinline__ float4 f4add(float4 a, float4 b) {
    return make_float4(a.x + b.x, a.y + b.y, a.z + b.z, a.w + b.w);
}
__device__ __forceinline__ float4 f4sub(float4 a, float4 b) {
    return make_float4(a.x - b.x, a.y - b.y, a.z - b.z, a.w - b.w);
}
__device__ __forceinline__ float4 f4mul(float4 a, float4 b) {
    return make_float4(a.x * b.x, a.y * b.y, a.z * b.z, a.w * b.w);
}

__global__ void zero_ws(double* p) { *p = 0.0; }

__global__ void finalize(const double* p, float* out) {
    out[0] = 1.0f - (float)(*p / NPIX);
}

__global__ void __launch_bounds__(128, 2)
ssim_main(const float* __restrict__ gt, const float* __restrict__ ni,
          double* __restrict__ acc_out)
{
    const int t   = threadIdx.x;      // 0..127
    const int c0  = t * 4;            // base column (0..508)
    const int img = blockIdx.y;
    const int R0  = blockIdx.x * TH;  // first output row of strip (mult of 8)
    const int R1  = min(R0 + TH, OH);

    const float C1 = 1e-4f;
    const float C2 = 9e-4f;

    const float* gx = gt + (size_t)img * (W * H) + c0;
    const float* gy = ni + (size_t)img * (W * H) + c0;

    // double-buffered vertical sums: [buf][quantity][column]; width 520 so
    // threads 126/127 can read past 512 (garbage, predicated out).
    __shared__ float vbuf[2][5][520];
    __shared__ float wpart[2];

    float4 ring_x[8], ring_y[8];
    float4 vsx  = make_float4(0, 0, 0, 0);
    float4 vsy  = make_float4(0, 0, 0, 0);
    float4 vsxx = make_float4(0, 0, 0, 0);
    float4 vsyy = make_float4(0, 0, 0, 0);
    float4 vsxy = make_float4(0, 0, 0, 0);

    // warm-up: rows R0..R0+6 -> ring slots 0..6; slot 7 = zeros (no row leaves
    // the window at r == R0).
#pragma unroll
    for (int k = 0; k < 7; ++k) {
        float4 x = ld4(gx + (size_t)(R0 + k) * W);
        float4 y = ld4(gy + (size_t)(R0 + k) * W);
        ring_x[k] = x; ring_y[k] = y;
        vsx  = f4add(vsx, x);
        vsy  = f4add(vsy, y);
        vsxx = f4add(vsxx, f4mul(x, x));
        vsyy = f4add(vsyy, f4mul(y, y));
        vsxy = f4add(vsxy, f4mul(x, y));
    }
    ring_x[7] = make_float4(0, 0, 0, 0);
    ring_y[7] = make_float4(0, 0, 0, 0);

    // prefetch first new row (R0+7 <= 487 < 512 always)
    float4 px = ld4(gx + (size_t)(R0 + 7) * W);
    float4 py = ld4(gy + (size_t)(R0 + 7) * W);

    float acc = 0.0f;

#define HORIZ(q, v) {                                                     \
        float4 n1 = *(float4*)&vbuf[b][q][c0 + 4];                        \
        float4 n2 = *(float4*)&vbuf[b][q][c0 + 8];                        \
        float s = v.x + v.y + v.z + v.w + n1.x + n1.y + n1.z + n1.w;      \
        B[q][0] = s;                                                      \
        s += n2.x - v.x; B[q][1] = s;                                     \
        s += n2.y - v.y; B[q][2] = s;                                     \
        s += n2.z - v.z; B[q][3] = s;                                     \
    }

#define ROWBODY(k, slot) {                                                \
        const int r = rbase + (k);                                        \
        if (r < R1) { /* block-uniform */                                 \
            float4 cx = px, cy = py;                                      \
            if (r + 1 < R1) { /* prefetch row r+8 (< 512 guaranteed) */   \
                px = ld4(gx + (size_t)(r + 8) * W);                       \
                py = ld4(gy + (size_t)(r + 8) * W);                       \
            }                                                             \
            float4 ox = ring_x[slot], oy = ring_y[slot];                  \
            vsx  = f4add(f4sub(vsx,  ox),           cx);                  \
            vsy  = f4add(f4sub(vsy,  oy),           cy);                  \
            vsxx = f4add(f4sub(vsxx, f4mul(ox, ox)), f4mul(cx, cx));      \
            vsyy = f4add(f4sub(vsyy, f4mul(oy, oy)), f4mul(cy, cy));      \
            vsxy = f4add(f4sub(vsxy, f4mul(ox, oy)), f4mul(cx, cy));      \
            ring_x[slot] = cx; ring_y[slot] = cy;                         \
            const int b = r & 1;                                          \
            *(float4*)&vbuf[b][0][c0] = vsx;                              \
            *(float4*)&vbuf[b][1][c0] = vsy;                              \
            *(float4*)&vbuf[b][2][c0] = vsxx;                             \
            *(float4*)&vbuf[b][3][c0] = vsyy;                             \
            *(float4*)&vbuf[b][4][c0] = vsxy;                             \
            __syncthreads();                                              \
            float B[5][4];                                                \
            HORIZ(0, vsx); HORIZ(1, vsy); HORIZ(2, vsxx);                 \
            HORIZ(3, vsyy); HORIZ(4, vsxy);                               \
            _Pragma("unroll")                                             \
            for (int j = 0; j < 4; ++j) {                                 \
                float Sx = B[0][j], Sy = B[1][j];                         \
                float Sxx = B[2][j], Syy = B[3][j], Sxy = B[4][j];        \
                float mu12 = Sx * Sy;                                     \
                float n1v = 2.0f * mu12 + C1;                             \
                float n2v = 2.0f * (Sxy - mu12) + C2;                     \
                float d1  = Sx * Sx + Sy * Sy + C1;                       \
                float d2  = (Sxx - Sx * Sx) + (Syy - Sy * Sy) + C2;       \
                float sv  = (n1v * n2v) / (d1 * d2);                      \
                if (c0 + j < OW) acc += sv;                               \
            }                                                             \
        }                                                                 \
    }

    // R0 and rbase are multiples of 8, so ring slot (r+7)&7 = (k+7)&7 (literal).
    for (int rbase = R0; rbase < R1; rbase += 8) {
        ROWBODY(0, 7)
        ROWBODY(1, 0)
        ROWBODY(2, 1)
        ROWBODY(3, 2)
        ROWBODY(4, 3)
        ROWBODY(5, 4)
        ROWBODY(6, 5)
        ROWBODY(7, 6)
    }

    // reduction: wave shuffle -> LDS -> one double atomic per block
#pragma unroll
    for (int off = 32; off > 0; off >>= 1) acc += __shfl_down(acc, off);
    const int wave = t >> 6, lane = t & 63;
    if (lane == 0) wpart[wave] = acc;
    __syncthreads();
    if (t == 0) atomicAdd(acc_out, (double)(wpart[0] + wpart[1]));
}

extern "C" void kernel_launch(void* const* d_in, const int* in_sizes, int n_in,
                              void* d_out, int out_size, void* d_ws, size_t ws_size,
                              hipStream_t stream) {
    const float* gt = (const float*)d_in[0];
    const float* ni = (const float*)d_in[1];
    double* acc = (double*)d_ws;   // 8 bytes of scratch, re-zeroed every call

    zero_ws<<<1, 1, 0, stream>>>(acc);
    dim3 grid(NSTRIP, NIMG);
    ssim_main<<<grid, 128, 0, stream>>>(gt, ni, acc);
    finalize<<<1, 1, 0, stream>>>(acc, (float*)d_out);
}